// Round 9
// baseline (360.085 us; speedup 1.0000x reference)
//
#include <hip/hip_runtime.h>
#include <hip/hip_bf16.h>
#include <math.h>

typedef __hip_bfloat16 bf16;
typedef __attribute__((ext_vector_type(8))) short short8;   // 8 x bf16 bits (4 VGPRs)
typedef __attribute__((ext_vector_type(4))) float f32x4;
typedef __attribute__((ext_vector_type(16))) float f32x16;

static constexpr int BB   = 2;
static constexpr int SS   = 2048;
static constexpr int DD   = 2048;
static constexpr int NH   = 16;
static constexpr int HDD  = 128;
static constexpr int LATD = 512;
static constexpr int MR   = BB * SS;   // 4096 token rows
static constexpr int QRS  = DD + LATD; // 2560: row stride of merged [Q | c_kv] buffer

#if __has_builtin(__builtin_amdgcn_exp2f)
#define EXP2F(x) __builtin_amdgcn_exp2f(x)
#else
#define EXP2F(x) exp2f(x)
#endif

__device__ __forceinline__ void async_cp16(const void* g, void* l) {
    __builtin_amdgcn_global_load_lds(
        (const __attribute__((address_space(1))) void*)g,
        (__attribute__((address_space(3))) void*)l, 16, 0, 0);
}

__device__ __forceinline__ unsigned short bf_bits(bf16 v) {
    union { bf16 b; unsigned short u; } cv; cv.b = v; return cv.u;
}

// ================= prep: cast x -> bf16 + transpose/cast Wq,Wdown,Wkup,Wvup =========
__global__ __launch_bounds__(256) void prep(
    const float* __restrict__ x, bf16* __restrict__ xb,
    const float* __restrict__ Wq, const float* __restrict__ Wdown,
    const float* __restrict__ Wkup, const float* __restrict__ Wvup,
    bf16* __restrict__ WqdT, bf16* __restrict__ WkvT) {
    __shared__ float tile[32][33];
    const int blk = blockIdx.x, tid = threadIdx.x;
    if (blk < 8192) {
        const int i = blk * 256 + tid;
        float4 v = ((const float4*)x)[i];
        ushort4 o;
        o.x = bf_bits(__float2bfloat16(v.x));
        o.y = bf_bits(__float2bfloat16(v.y));
        o.z = bf_bits(__float2bfloat16(v.z));
        o.w = bf_bits(__float2bfloat16(v.w));
        ((ushort4*)xb)[i] = o;
        return;
    }
    const float* in; bf16* out; int rows, cols, bx, by;
    if (blk < 12288) {
        const int l = blk - 8192;  in = Wq;    out = WqdT;
        rows = DD;   cols = DD;    bx = l & 63; by = l >> 6;
    } else if (blk < 13312) {
        const int l = blk - 12288; in = Wdown; out = WqdT + (size_t)DD * DD;
        rows = DD;   cols = LATD;  bx = l & 15; by = l >> 4;
    } else if (blk < 14336) {
        const int l = blk - 13312; in = Wkup;  out = WkvT;
        rows = LATD; cols = DD;    bx = l & 63; by = l >> 6;
    } else {
        const int l = blk - 14336; in = Wvup;  out = WkvT + (size_t)DD * LATD;
        rows = LATD; cols = DD;    bx = l & 63; by = l >> 6;
    }
    const int tx = tid & 31, ty = tid >> 5;
    const int c0 = bx * 32, r0 = by * 32;
    for (int i = 0; i < 32; i += 8)
        tile[ty + i][tx] = in[(size_t)(r0 + ty + i) * cols + c0 + tx];
    __syncthreads();
    for (int i = 0; i < 32; i += 8)
        out[(size_t)(c0 + ty + i) * rows + r0 + tx] =
            __float2bfloat16(tile[tx][ty + i]);
}

// ===== gemm8p: m201-style 8-phase 256x256 GEMM, BK=64, 8 waves (2Mx4N) =====
// Per K-tile 4 phases: {ds_read subtile | stage 1 half-tile | barrier | lgkmcnt(0)
// | setprio + 16 MFMA (one C-quadrant) | barrier}. Quadrant order Q1(m0-3,n0-1)
// Q2(m0-3,n2-3) Q3(m4-7,n2-3) Q4(m4-7,n0-1): no frag re-read; A-half frees after
// Q3, B-half after Q2. Stage schedule per tile tt: P1:(tt+1).A0 P2:(tt+1).A1
// P3:(tt+2).B0 P4:(tt+2).B1 -> counted vmcnt(4) at P4 only (never 0 in hot loop).
// T21 swizzle: linear gload_lds dest + inverse-XOR global source granule
// (g^(r&7)); ds_read applies the same XOR. LDS 128KB -> 1 block/CU.
template <bool OUT_F32>
__global__ __launch_bounds__(512) void gemm8p(
    const bf16* __restrict__ A, const bf16* __restrict__ Bt,
    void* __restrict__ Cout, int M, int N, int K, int lda, int ldb, int ldc) {
    __shared__ __align__(16) char smem[131072];  // [pt][A/B][half 16KB]
    const int tid  = threadIdx.x;
    const int lane = tid & 63, wave = tid >> 6;
    const int quad = lane >> 4, l16 = lane & 15;
    const int wm = wave >> 2, wn = wave & 3;      // 2M x 4N

    const int nx = N >> 8, ny = M >> 8;
    const int nwg = nx * ny;
    const int wg   = ((blockIdx.x & 7) * (nwg >> 3)) + (blockIdx.x >> 3);
    const int nig  = nx << 3;
    const int brow = ((wg / nig) << 3) + (wg & 7);
    const int bcol = (wg % nig) >> 3;
    const int row0 = brow << 8, col0 = bcol << 8;

    const int NT = K >> 6;                        // 64-wide K-tiles (even here)

    // stage one 16KB half-tile (2 gload_lds/thread, linear LDS dest,
    // inverse-swizzled source granule)
    auto stageH = [&](int tt, int isB, int h) {
        char* dst0 = smem + (size_t)((((tt & 1) << 1) | isB) * 32768 + h * 16384)
                     + tid * 16;
#pragma unroll
        for (int l = 0; l < 2; ++l) {
            const int r  = l * 64 + (tid >> 3);
            const int gs = (tid & 7) ^ (r & 7);
            const bf16* src = isB
                ? Bt + (size_t)(col0 + h * 128 + r) * ldb + tt * 64 + gs * 8
                : A  + (size_t)(row0 + h * 128 + r) * lda + tt * 64 + gs * 8;
            async_cp16(src, dst0 + l * 8192);
        }
    };

    f32x4 acc[8][4];
#pragma unroll
    for (int m = 0; m < 8; ++m)
#pragma unroll
        for (int n = 0; n < 4; ++n)
#pragma unroll
            for (int r = 0; r < 4; ++r) acc[m][n][r] = 0.f;

    // prologue (FIFO order matches steady state): t0.B0,B1,A0,A1, t1.B0,B1
    stageH(0, 1, 0); stageH(0, 1, 1); stageH(0, 0, 0); stageH(0, 0, 1);
    stageH(1, 1, 0); stageH(1, 1, 1);
    asm volatile("s_waitcnt vmcnt(4)" ::: "memory");   // t0 resident; t1.B in flight
    __builtin_amdgcn_s_barrier();

    for (int tt = 0; tt < NT; ++tt) {
        const int pt = tt & 1;
        const char* Abase = smem + (size_t)((pt << 1) * 32768 + wm * 16384);
        const char* Bbase = smem + (size_t)(((pt << 1) | 1) * 32768
                                            + (wn >> 1) * 16384);
        short8 b01[2][2], b23[2][2], am[4][2];

        // ---- P1 (Q1: m0-3 x n0-1): read B n0-1 + A m0-3; stage (tt+1).A0 ----
#pragma unroll
        for (int n = 0; n < 2; ++n)
#pragma unroll
            for (int ks = 0; ks < 2; ++ks) {
                const int r = ((wn & 1) << 6) + n * 16 + l16;
                b01[n][ks] = *(const short8*)
                    (Bbase + r * 128 + ((((ks << 2) | quad) ^ (r & 7)) << 4));
            }
#pragma unroll
        for (int m = 0; m < 4; ++m)
#pragma unroll
            for (int ks = 0; ks < 2; ++ks) {
                const int r = m * 16 + l16;
                am[m][ks] = *(const short8*)
                    (Abase + r * 128 + ((((ks << 2) | quad) ^ (r & 7)) << 4));
            }
        if (tt + 1 < NT) stageH(tt + 1, 0, 0);
        __builtin_amdgcn_s_barrier();
        __builtin_amdgcn_s_waitcnt(0xc07f);
        __builtin_amdgcn_s_setprio(1);
#pragma unroll
        for (int m = 0; m < 4; ++m)
#pragma unroll
            for (int n = 0; n < 2; ++n)
#pragma unroll
                for (int ks = 0; ks < 2; ++ks)
                    acc[m][n] = __builtin_amdgcn_mfma_f32_16x16x32_bf16(
                        am[m][ks], b01[n][ks], acc[m][n], 0, 0, 0);
        __builtin_amdgcn_s_setprio(0);
        __builtin_amdgcn_s_barrier();

        // ---- P2 (Q2: m0-3 x n2-3): read B n2-3; stage (tt+1).A1 ----
#pragma unroll
        for (int n = 0; n < 2; ++n)
#pragma unroll
            for (int ks = 0; ks < 2; ++ks) {
                const int r = ((wn & 1) << 6) + (n + 2) * 16 + l16;
                b23[n][ks] = *(const short8*)
                    (Bbase + r * 128 + ((((ks << 2) | quad) ^ (r & 7)) << 4));
            }
        if (tt + 1 < NT) stageH(tt + 1, 0, 1);
        __builtin_amdgcn_s_barrier();
        __builtin_amdgcn_s_waitcnt(0xc07f);
        __builtin_amdgcn_s_setprio(1);
#pragma unroll
        for (int m = 0; m < 4; ++m)
#pragma unroll
            for (int n = 0; n < 2; ++n)
#pragma unroll
                for (int ks = 0; ks < 2; ++ks)
                    acc[m][n + 2] = __builtin_amdgcn_mfma_f32_16x16x32_bf16(
                        am[m][ks], b23[n][ks], acc[m][n + 2], 0, 0, 0);
        __builtin_amdgcn_s_setprio(0);
        __builtin_amdgcn_s_barrier();

        // ---- P3 (Q3: m4-7 x n2-3): read A m4-7; stage (tt+2).B0 ----
#pragma unroll
        for (int m = 0; m < 4; ++m)
#pragma unroll
            for (int ks = 0; ks < 2; ++ks) {
                const int r = (m + 4) * 16 + l16;
                am[m][ks] = *(const short8*)
                    (Abase + r * 128 + ((((ks << 2) | quad) ^ (r & 7)) << 4));
            }
        if (tt + 2 < NT) stageH(tt + 2, 1, 0);
        __builtin_amdgcn_s_barrier();
        __builtin_amdgcn_s_waitcnt(0xc07f);
        __builtin_amdgcn_s_setprio(1);
#pragma unroll
        for (int m = 0; m < 4; ++m)
#pragma unroll
            for (int n = 0; n < 2; ++n)
#pragma unroll
                for (int ks = 0; ks < 2; ++ks)
                    acc[m + 4][n + 2] = __builtin_amdgcn_mfma_f32_16x16x32_bf16(
                        am[m][ks], b23[n][ks], acc[m + 4][n + 2], 0, 0, 0);
        __builtin_amdgcn_s_setprio(0);
        __builtin_amdgcn_s_barrier();

        // ---- P4 (Q4: m4-7 x n0-1): no reads; stage (tt+2).B1; counted vmcnt ----
        if (tt + 2 < NT) stageH(tt + 2, 1, 1);
        __builtin_amdgcn_s_barrier();
        __builtin_amdgcn_s_setprio(1);
#pragma unroll
        for (int m = 0; m < 4; ++m)
#pragma unroll
            for (int n = 0; n < 2; ++n)
#pragma unroll
                for (int ks = 0; ks < 2; ++ks)
                    acc[m + 4][n] = __builtin_amdgcn_mfma_f32_16x16x32_bf16(
                        am[m][ks], b01[n][ks], acc[m + 4][n], 0, 0, 0);
        __builtin_amdgcn_s_setprio(0);
        if (tt + 2 < NT) asm volatile("s_waitcnt vmcnt(4)" ::: "memory");
        else             asm volatile("s_waitcnt vmcnt(0)" ::: "memory");
        __builtin_amdgcn_s_barrier();
    }

    const int rbase = row0 + wm * 128 + quad * 4;
    const int cbase = col0 + wn * 64 + l16;
    if (OUT_F32) {
        float* C = (float*)Cout;
#pragma unroll
        for (int m = 0; m < 8; ++m)
#pragma unroll
            for (int n = 0; n < 4; ++n)
#pragma unroll
                for (int r = 0; r < 4; ++r)
                    C[(size_t)(rbase + m * 16 + r) * ldc + cbase + n * 16] = acc[m][n][r];
    } else {
        bf16* C = (bf16*)Cout;
#pragma unroll
        for (int m = 0; m < 8; ++m)
#pragma unroll
            for (int n = 0; n < 4; ++n)
#pragma unroll
                for (int r = 0; r < 4; ++r)
                    C[(size_t)(rbase + m * 16 + r) * ldc + cbase + n * 16] =
                        __float2bfloat16(acc[m][n][r]);
    }
}

// ------- 2-phase 128-tile GEMM (kept for GEMM2: K=512, 1024 blocks, RoPE fused) -------
template <bool OUT_F32, bool ROPE>
__global__ __launch_bounds__(256) void gemm_bt(
    const bf16* __restrict__ A, const bf16* __restrict__ Bt,
    void* __restrict__ Cout, int M, int N, int K, int lda, int ldb, int ldc,
    const float* __restrict__ freqs) {
    __shared__ bf16 As[2][128 * 32];
    __shared__ bf16 Bs[2][128 * 32];
    const int tid  = threadIdx.x;
    const int lane = tid & 63, wave = tid >> 6;
    const int quad = lane >> 4, l16 = lane & 15;

    const int nx = N >> 7, ny = M >> 7;
    const int nwg = nx * ny;
    const int wg  = ((blockIdx.x & 7) * (nwg >> 3)) + (blockIdx.x >> 3);
    const int nig = nx << 3;
    const int brow = ((wg / nig) << 3) + (wg & 7);
    const int bcol = (wg % nig) >> 3;
    const int row0 = brow * 128, col0 = bcol * 128;

    const int wm = (wave >> 1) * 64, wn = (wave & 1) * 64;
    const int srow = lane >> 2;
    const int scol = (lane & 3) * 8;

    f32x4 acc[4][4];
    for (int i = 0; i < 4; ++i)
        for (int j = 0; j < 4; ++j)
            for (int r = 0; r < 4; ++r) acc[i][j][r] = 0.f;

    auto stage = [&](int k0, int bufi) {
        for (int c = 0; c < 2; ++c) {
            const int chunk = wave * 2 + c;
            const int r = chunk * 16 + srow;
            async_cp16(A  + (size_t)(row0 + r) * lda + k0 + scol, &As[bufi][chunk * 512]);
            async_cp16(Bt + (size_t)(col0 + r) * ldb + k0 + scol, &Bs[bufi][chunk * 512]);
        }
    };

    const int nk = K / 32;
    stage(0, 0);
    for (int ki = 0; ki < nk; ++ki) {
        __syncthreads();                    // drains stage ki; frees buf (ki+1)&1
        if (ki + 1 < nk) stage((ki + 1) * 32, (ki + 1) & 1);
        const int bi = ki & 1;
        short8 af[4], bfr[4];
        for (int t = 0; t < 4; ++t) {
            af[t]  = *(const short8*)&As[bi][(wm + t * 16 + l16) * 32 + quad * 8];
            bfr[t] = *(const short8*)&Bs[bi][(wn + t * 16 + l16) * 32 + quad * 8];
        }
        for (int i = 0; i < 4; ++i)
            for (int j = 0; j < 4; ++j)
                acc[i][j] = __builtin_amdgcn_mfma_f32_16x16x32_bf16(
                    af[i], bfr[j], acc[i][j], 0, 0, 0);
    }

    const int rbase = row0 + wm + quad * 4;
    const int cbase = col0 + wn + l16;
    if (OUT_F32) {
        float* C = (float*)Cout;
        for (int i = 0; i < 4; ++i)
            for (int j = 0; j < 4; ++j)
                for (int r = 0; r < 4; ++r)
                    C[(size_t)(rbase + i * 16 + r) * ldc + cbase + j * 16] = acc[i][j][r];
    } else if (ROPE && col0 < 2048) {
        // K-half of GEMM2: RoPE fused on f32 acc (partner value from lane^1)
        bf16* C = (bf16*)Cout;
        for (int i = 0; i < 4; ++i)
            for (int r = 0; r < 4; ++r) {
                const int s = (rbase + i * 16 + r) & (SS - 1);
                const float* fro = freqs + (size_t)s * 64;
                for (int j = 0; j < 4; ++j) {
                    const int d = wn + j * 16 + l16;     // col&127 (no wrap)
                    const float f = fro[d >> 1];
                    const float cs = __cosf(f), sn = __sinf(f);
                    const float v  = acc[i][j][r];
                    const float vp = __shfl_xor(v, 1);
                    const float o  = (l16 & 1) ? (vp * sn + v * cs)
                                               : (v * cs - vp * sn);
                    C[(size_t)(rbase + i * 16 + r) * ldc + cbase + j * 16] =
                        __float2bfloat16(o);
                }
            }
    } else {
        bf16* C = (bf16*)Cout;
        for (int i = 0; i < 4; ++i)
            for (int j = 0; j < 4; ++j)
                for (int r = 0; r < 4; ++r)
                    C[(size_t)(rbase + i * 16 + r) * ldc + cbase + j * 16] =
                        __float2bfloat16(acc[i][j][r]);
    }
}

// ====== tvrope: V pre-transpose + Wo transpose, one launch ======
__global__ __launch_bounds__(256) void tvrope(
    bf16* __restrict__ KV, bf16* __restrict__ VT,
    const float* __restrict__ Wo, bf16* __restrict__ WoT) {
    __shared__ __align__(16) char sm[64 * 74 * 2];   // also holds float[32][33]
    const int blk = blockIdx.x, tid = threadIdx.x;
    if (blk < 2048) {
        bf16 (*t)[74] = (bf16(*)[74])sm;
        const int bx = blk & 31, byy = (blk >> 5) & 1, bh = blk >> 6;
        const int s0 = bx * 64, d0 = byy * 64;
        const int b = bh >> 4, h = bh & 15;
        const bf16* src = KV + (size_t)b * SS * 4096 + 2048 + h * 128 + d0;
        for (int p = 0; p < 2; ++p) {
            const int s = p * 32 + (tid >> 3), dc = (tid & 7) * 8;
            short8 v = *(const short8*)(src + (size_t)(s0 + s) * 4096 + dc);
            const bf16* ve = (const bf16*)&v;
            for (int e = 0; e < 8; ++e) t[s][dc + e] = ve[e];
        }
        __syncthreads();
        bf16* dst = VT + ((size_t)bh * HDD + d0) * SS + s0;
        for (int p = 0; p < 2; ++p) {
            const int d = p * 32 + (tid >> 3), g = tid & 7;
            short8 v; bf16* ve = (bf16*)&v;
            for (int e = 0; e < 8; ++e) ve[e] = t[g * 8 + e][d];
            const int gp = g ^ (d & 7);
            *(short8*)(dst + (size_t)d * SS + gp * 8) = v;
        }
        return;
    }
    {   // Wo transpose (WoT aliases WqdT: safe, QC gemm already retired in stream order)
        float (*tile)[33] = (float(*)[33])sm;
        const int l = blk - 2048;
        const int bx = l & 63, by = l >> 6;
        const int tx = tid & 31, ty = tid >> 5;
        const int c0 = bx * 32, r0 = by * 32;
        for (int i = 0; i < 32; i += 8)
            tile[ty + i][tx] = Wo[(size_t)(r0 + ty + i) * DD + c0 + tx];
        __syncthreads();
        for (int i = 0; i < 32; i += 8)
            WoT[(size_t)(c0 + ty + i) * DD + r0 + tx] =
                __float2bfloat16(tile[tx][ty + i]);
    }
}

// ------------- causal flash attention v2b (proven 74.4 us): 4 waves, 32x32 MFMA,
// swapped QK^T, in-register softmax. Cross-half exchanges via __shfl_xor;
// P->bf16 via scalar casts. Lane owns one q-row (col l32 of S^T). LDS 66 KB.
__global__ __launch_bounds__(256, 2) void flash_attn(
    const bf16* __restrict__ QC, const bf16* __restrict__ KV,
    const bf16* __restrict__ VTg, const float* __restrict__ freqs,
    bf16* __restrict__ O) {
    const int j = blockIdx.x;
    const int bh = (j >> 3) & 31, q3 = j & 7;
    const int qt = (j & 256) ? q3 : 15 - q3;
    const int h = bh & (NH - 1), b = bh >> 4;
    const int q0 = qt * 128;
    const int tid = threadIdx.x, lane = tid & 63, wave = tid >> 6;
    const int l32 = lane & 31, hi = lane >> 5;

    __shared__ __align__(16) char smem[66048];
    bf16*  KsB  = (bf16*)smem;              // [2][64*128]
    bf16*  VtB  = (bf16*)(smem + 32768);    // [2][128*64]
    float* RedS = (float*)(smem + 65536);   // [4][32]

    const bf16* Kb  = KV  + (size_t)b * SS * 4096 + h * HDD;
    const bf16* VTb = VTg + (size_t)bh * HDD * SS;

    // ---- Q B-frags (col=q=l32, k-elems d=dk*16+hi*8+e), RoPE+scale fused ----
    const float QS = 0.08838834764831845f * 1.4426950408889634f;  // 1/sqrt(HD)*log2e
    const int qrow = q0 + wave * 32 + l32;
    short8 qf[8];
    {
        const bf16* qp = QC + (size_t)(b * SS + qrow) * QRS + h * HDD;
#pragma unroll
        for (int dk = 0; dk < 8; ++dk) {
            short8 v = *(const short8*)(qp + dk * 16 + hi * 8);
            const float4 f = *(const float4*)&freqs[(size_t)qrow * 64 + dk * 8 + hi * 4];
            const float fr[4] = {f.x, f.y, f.z, f.w};
            const bf16* ve = (const bf16*)&v;
            bf16* oe = (bf16*)&qf[dk];
#pragma unroll
            for (int i2 = 0; i2 < 4; ++i2) {
                const float cs = __cosf(fr[i2]), sn = __sinf(fr[i2]);
                const float t0 = __bfloat162float(ve[2 * i2]);
                const float t1 = __bfloat162float(ve[2 * i2 + 1]);
                oe[2 * i2]     = __float2bfloat16((t0 * cs - t1 * sn) * QS);
                oe[2 * i2 + 1] = __float2bfloat16((t0 * sn + t1 * cs) * QS);
            }
        }
    }

    // ---- staging: K with inverse-swizzled source (linear LDS dest),
    //      V straight copy of pre-swizzled VTg rows ----
    auto stage = [&](int kt, int bufi) {
        const int k0 = kt * 64;
#pragma unroll
        for (int ii = 0; ii < 4; ++ii) {
            const int i = wave * 4 + ii;
            const int krow = 4 * i + (lane >> 4);
            const int csrc = (lane & 15) ^ (krow & 7);
            async_cp16(Kb + (size_t)(k0 + krow) * 4096 + csrc * 8,
                       KsB + bufi * 8192 + i * 512);
            const int d = 8 * i + (lane >> 3);
            async_cp16(VTb + (size_t)d * SS + k0 + (lane & 7) * 8,
                       VtB + bufi * 8192 + i * 512);
        }
    };

    f32x16 accO[4];
#pragma unroll
    for (int d = 0; d < 4; ++d)
#pragma unroll
        for (int r = 0; r < 16; ++r) accO[d][r] = 0.f;
    float m_r = -1e30f, l_r = 0.f;

    const int ktMax = 2 * qt + 1;
    const int qwb = q0 + wave * 32;      // wave's first q row

    stage(0, 0);
    for (int kt = 0; kt <= ktMax; ++kt) {
        const int k0 = kt * 64;
        __syncthreads();                    // drains stage kt; frees buf (kt+1)&1
        if (kt < ktMax) stage(kt + 1, (kt + 1) & 1);
        const int bi = kt & 1;

        if (k0 > qwb + 31) continue;        // tile entirely above diagonal (wave-uniform)

        // ---- S^T = K Q^T : lane holds 32 kv-scores for q-row l32 ----
        f32x16 st[2];
#pragma unroll
        for (int t = 0; t < 2; ++t)
#pragma unroll
            for (int r = 0; r < 16; ++r) st[t][r] = 0.f;
        __builtin_amdgcn_s_setprio(1);
#pragma unroll
        for (int dk = 0; dk < 8; ++dk)
#pragma unroll
            for (int t = 0; t < 2; ++t) {
                const int rd = t * 32 + l32;
                short8 kf = *(const short8*)
                    &KsB[bi * 8192 + rd * 128 + ((((dk << 1) | hi) ^ (rd & 7)) << 3)];
                st[t] = __builtin_amdgcn_mfma_f32_32x32x16_bf16(
                    kf, qf[dk], st[t], 0, 0, 0);
            }
        __builtin_amdgcn_s_setprio(0);

        float p[32];
#pragma unroll
        for (int t = 0; t < 2; ++t)
#pragma unroll
            for (int r = 0; r < 16; ++r) p[t * 16 + r] = st[t][r];

        // ---- causal mask (boundary tiles only; wave-uniform branch) ----
        if (k0 + 63 > qwb) {
#pragma unroll
            for (int t = 0; t < 2; ++t)
#pragma unroll
                for (int r = 0; r < 16; ++r) {
                    const int kv = k0 + t * 32 + (r & 3) + 8 * (r >> 2) + 4 * hi;
                    if (kv > qrow) p[t * 16 + r] = -1e30f;
                }
        }

        // ---- row max: lane-local tree + cross-half shfl ----
        float mt[16];
#pragma unroll
        for (int n = 0; n < 16; ++n) mt[n] = fmaxf(p[n], p[n + 16]);
#pragma unroll
        for (int n = 0; n < 8; ++n) mt[n] = fmaxf(mt[n], mt[n + 8]);
#pragma unroll
        for (int n = 0; n < 4; ++n) mt[n] = fmaxf(mt[n], mt[n + 4]);
        float mx = fmaxf(fmaxf(mt[0], mt[1]), fmaxf(mt[2], mt[3]));
        const float rmax = fmaxf(mx, __shfl_xor(mx, 32));

        // ---- defer-max (T13): rescale only when max grows > 2^8 ----
        const bool grow = rmax > m_r + 8.f;
        if (__any(grow)) {
            const float mnew = fmaxf(m_r, rmax);
            const float alpha = EXP2F(m_r - mnew);
            m_r = mnew;
            l_r *= alpha;
            RedS[wave * 32 + l32] = alpha;      // both halves write identical value
            __builtin_amdgcn_s_waitcnt(0xc07f); // lgkmcnt(0): own-wave writes visible
#pragma unroll
            for (int r = 0; r < 16; ++r) {
                const float av = RedS[wave * 32 + ((r & 3) + 8 * (r >> 2) + 4 * hi)];
#pragma unroll
                for (int d = 0; d < 4; ++d) accO[d][r] *= av;
            }
        }

        // ---- P = exp2(S - m); row sum (tree + cross-half shfl) ----
#pragma unroll
        for (int r = 0; r < 32; ++r) p[r] = EXP2F(p[r] - m_r);
        float sa[16];
#pragma unroll
        for (int n = 0; n < 16; ++n) sa[n] = p[n] + p[n + 16];
#pragma unroll
        for (int n = 0; n < 8; ++n) sa[n] += sa[n + 8];
#pragma unroll
        for (int n = 0; n < 4; ++n) sa[n] += sa[n + 4];
        float ps = (sa[0] + sa[1]) + (sa[2] + sa[3]);
        l_r += ps + __shfl_xor(ps, 32);

        // ---- P -> packed bf16 pairs (scalar casts; compiler emits cvt_pk) ----
        unsigned int pk[16];
#pragma unroll
        for (int n = 0; n < 16; ++n) {
            const unsigned int lo = bf_bits(__float2bfloat16(p[2 * n]));
            const unsigned int hl = bf_bits(__float2bfloat16(p[2 * n + 1]));
            pk[n] = lo | (hl << 16);
        }

        // ---- O += P V  (A-frags assembled via cross-half shfl) ----
#pragma unroll
        for (int m = 0; m < 4; ++m) {
            const int A0 = 4 * m;
            const unsigned int op0 = __shfl_xor(pk[A0 + 0], 32);
            const unsigned int op1 = __shfl_xor(pk[A0 + 1], 32);
            const unsigned int op2 = __shfl_xor(pk[A0 + 2], 32);
            const unsigned int op3 = __shfl_xor(pk[A0 + 3], 32);
            union { unsigned int w[4]; short8 s; } fr;
            fr.w[0] = hi ? op2 : pk[A0 + 0];
            fr.w[1] = hi ? op3 : pk[A0 + 1];
            fr.w[2] = hi ? pk[A0 + 2] : op0;
            fr.w[3] = hi ? pk[A0 + 3] : op1;
            __builtin_amdgcn_s_setprio(1);
#pragma unroll
            for (int db = 0; db < 4; ++db) {
                const int d = db * 32 + l32;
                short8 vf = *(const short8*)
                    &VtB[bi * 8192 + d * 64 + ((((m << 1) | hi) ^ (d & 7)) << 3)];
                accO[db] = __builtin_amdgcn_mfma_f32_32x32x16_bf16(
                    fr.s, vf, accO[db], 0, 0, 0);
            }
            __builtin_amdgcn_s_setprio(0);
        }
    }

    // ---- epilogue: 1/l per q-row, LDS bounce, coalesced bf16 stores ----
    const float invl = 1.f / l_r;
    RedS[wave * 32 + l32] = invl;
    __builtin_amdgcn_s_waitcnt(0xc07f);     // lgkmcnt(0): own-wave writes visible
    bf16* Ob = O + (size_t)b * SS * DD + h * HDD;
#pragma unroll
    for (int r = 0; r < 16; ++r) {
        const int row = (r & 3) + 8 * (r >> 2) + 4 * hi;
        const float iv = RedS[wave * 32 + row];
        const size_t ro = (size_t)(q0 + wave * 32 + row) * DD;
#pragma unroll
        for (int db = 0; db < 4; ++db)
            Ob[ro + db * 32 + l32] = __float2bfloat16(accO[db][r] * iv);
    }
}

extern "C" void kernel_launch(void* const* d_in, const int* in_sizes, int n_in,
                              void* d_out, int out_size, void* d_ws, size_t ws_size,
                              hipStream_t stream) {
    (void)in_sizes; (void)n_in; (void)out_size; (void)ws_size;
    const float* x     = (const float*)d_in[0];
    const float* freqs = (const float*)d_in[1];
    // d_in[2] = mask: exactly causal 0/-1e9 -> applied analytically in flash_attn
    const float* Wq    = (const float*)d_in[3];
    const float* Wdown = (const float*)d_in[4];
    const float* Wkup  = (const float*)d_in[5];
    const float* Wvup  = (const float*)d_in[6];
    const float* Wo    = (const float*)d_in[7];
    float* out = (float*)d_out;

    char* ws = (char*)d_ws;
    size_t off = 0;
    auto take = [&](size_t bytes) -> void* {
        void* p = ws + off;
        off += (bytes + 255) & ~(size_t)255;
        return p;
    };
    bf16* xb    = (bf16*)take((size_t)MR * DD * 2);         // 16.8 MB (later: attn)
    bf16* WqdT  = (bf16*)take((size_t)QRS * DD * 2);        // 10.5 MB (later: WoT)
    bf16* WkvT  = (bf16*)take((size_t)2 * DD * LATD * 2);   //  4.2 MB
    bf16* QC    = (bf16*)take((size_t)MR * QRS * 2);        // 21.0 MB [Q 2048 | ckv 512]
    bf16* KVb   = (bf16*)take((size_t)MR * 2 * DD * 2);     // 33.6 MB [tok][K | V]
    bf16* VTg   = (bf16*)take((size_t)BB * NH * HDD * SS * 2); // 16.8 MB (~103 MB total)
    bf16* attn  = xb;      // xb dead after QC gemm
    bf16* WoT   = WqdT;    // WqdT dead after QC gemm

    // cast x + all 4 early weight transposes in one launch
    prep<<<15360, 256, 0, stream>>>(x, xb, Wq, Wdown, Wkup, Wvup, WqdT, WkvT);

    // [Q | c_kv] = x [Wq | Wdown]   (M=4096, N=2560, K=2048) -> 160 blocks, 8-phase
    gemm8p<false><<<(QRS / 256) * (MR / 256), 512, 0, stream>>>(
        xb, WqdT, QC, MR, QRS, DD, DD, DD, QRS);
    // [K | V] = c_kv [Wkup | Wvup]  (M=4096, N=4096, K=512) -> 1024 blocks, 2-phase
    // K-half gets RoPE fused in the epilogue.
    gemm_bt<false, true><<<(2 * DD / 128) * (MR / 128), 256, 0, stream>>>(
        QC + DD, WkvT, KVb, MR, 2 * DD, LATD, QRS, LATD, 2 * DD, freqs);

    // V transpose + Wo transpose, one launch
    tvrope<<<6144, 256, 0, stream>>>(KVb, VTg, Wo, WoT);

    flash_attn<<<512, 256, 0, stream>>>(QC, KVb, VTg, freqs, attn);

    // out = attn Wo (fp32 epilogue straight to d_out)  -> 128 blocks, 8-phase
    gemm8p<true><<<(DD / 256) * (MR / 256), 512, 0, stream>>>(
        attn, WoT, out, MR, DD, DD, DD, DD, DD);
}

// Round 10
// 336.785 us; speedup vs baseline: 1.0692x; 1.0692x over previous
//
#include <hip/hip_runtime.h>
#include <hip/hip_bf16.h>
#include <math.h>

typedef __hip_bfloat16 bf16;
typedef __attribute__((ext_vector_type(8))) short short8;   // 8 x bf16 bits (4 VGPRs)
typedef __attribute__((ext_vector_type(4))) float f32x4;
typedef __attribute__((ext_vector_type(16))) float f32x16;

static constexpr int BB   = 2;
static constexpr int SS   = 2048;
static constexpr int DD   = 2048;
static constexpr int NH   = 16;
static constexpr int HDD  = 128;
static constexpr int LATD = 512;
static constexpr int MR   = BB * SS;   // 4096 token rows
static constexpr int QRS  = DD + LATD; // 2560: row stride of merged [Q | c_kv] buffer

#if __has_builtin(__builtin_amdgcn_exp2f)
#define EXP2F(x) __builtin_amdgcn_exp2f(x)
#else
#define EXP2F(x) exp2f(x)
#endif

__device__ __forceinline__ void async_cp16(const void* g, void* l) {
    __builtin_amdgcn_global_load_lds(
        (const __attribute__((address_space(1))) void*)g,
        (__attribute__((address_space(3))) void*)l, 16, 0, 0);
}

__device__ __forceinline__ unsigned short bf_bits(bf16 v) {
    union { bf16 b; unsigned short u; } cv; cv.b = v; return cv.u;
}

// ====== prep: cast x -> bf16 + transpose/cast Wq,Wdown,Wkup,Wvup,Wo (one launch) ======
__global__ __launch_bounds__(256) void prep(
    const float* __restrict__ x, bf16* __restrict__ xb,
    const float* __restrict__ Wq, const float* __restrict__ Wdown,
    const float* __restrict__ Wkup, const float* __restrict__ Wvup,
    const float* __restrict__ Wo,
    bf16* __restrict__ WqdT, bf16* __restrict__ WkvT, bf16* __restrict__ WoT) {
    __shared__ float tile[32][33];
    const int blk = blockIdx.x, tid = threadIdx.x;
    if (blk < 8192) {
        const int i = blk * 256 + tid;
        float4 v = ((const float4*)x)[i];
        ushort4 o;
        o.x = bf_bits(__float2bfloat16(v.x));
        o.y = bf_bits(__float2bfloat16(v.y));
        o.z = bf_bits(__float2bfloat16(v.z));
        o.w = bf_bits(__float2bfloat16(v.w));
        ((ushort4*)xb)[i] = o;
        return;
    }
    const float* in; bf16* out; int rows, cols, bx, by;
    if (blk < 12288) {
        const int l = blk - 8192;  in = Wq;    out = WqdT;
        rows = DD;   cols = DD;    bx = l & 63; by = l >> 6;
    } else if (blk < 13312) {
        const int l = blk - 12288; in = Wdown; out = WqdT + (size_t)DD * DD;
        rows = DD;   cols = LATD;  bx = l & 15; by = l >> 4;
    } else if (blk < 14336) {
        const int l = blk - 13312; in = Wkup;  out = WkvT;
        rows = LATD; cols = DD;    bx = l & 63; by = l >> 6;
    } else if (blk < 15360) {
        const int l = blk - 14336; in = Wvup;  out = WkvT + (size_t)DD * LATD;
        rows = LATD; cols = DD;    bx = l & 63; by = l >> 6;
    } else {
        const int l = blk - 15360; in = Wo;    out = WoT;
        rows = DD;   cols = DD;    bx = l & 63; by = l >> 6;
    }
    const int tx = tid & 31, ty = tid >> 5;
    const int c0 = bx * 32, r0 = by * 32;
    for (int i = 0; i < 32; i += 8)
        tile[ty + i][tx] = in[(size_t)(r0 + ty + i) * cols + c0 + tx];
    __syncthreads();
    for (int i = 0; i < 32; i += 8)
        out[(size_t)(c0 + ty + i) * rows + r0 + tx] =
            __float2bfloat16(tile[tx][ty + i]);
}

// ------- double-buffered GEMM: C[M][N] = A[M][K(lda)] * Bt[N][K(ldb)]^T -------
// 1D grid; XCD-chunked bijective remap + group-of-8-rows supertile (R6 winner).
// KVMODE (GEMM2): col0<2048 -> K-half with RoPE fused on f32 acc (partner from
// lane^1, pairs are adjacent lanes); col0>=2048 -> V-half written DIRECTLY as
// V^T into VTg[bh][d][s] with the flash-compatible granule swizzle pos=g^(d&7)
// (acc[i][j][0..3] = 4 consecutive s at one d = one 8B store). Kills the
// separate V materialize + transpose pass entirely.
template <bool OUT_F32, bool KVMODE>
__global__ __launch_bounds__(256) void gemm_bt(
    const bf16* __restrict__ A, const bf16* __restrict__ Bt,
    void* __restrict__ Cout, int M, int N, int K, int lda, int ldb, int ldc,
    const float* __restrict__ freqs, bf16* __restrict__ VTg) {
    __shared__ bf16 As[2][128 * 32];
    __shared__ bf16 Bs[2][128 * 32];
    const int tid  = threadIdx.x;
    const int lane = tid & 63, wave = tid >> 6;
    const int quad = lane >> 4, l16 = lane & 15;

    const int nx = N >> 7, ny = M >> 7;
    const int nwg = nx * ny;
    // XCD-contiguous chunk (blocks round-robin XCDs by blockIdx%8)
    const int wg  = ((blockIdx.x & 7) * (nwg >> 3)) + (blockIdx.x >> 3);
    // grouped supertile: sweep 8 rows, then next column
    const int nig = nx << 3;                 // blocks per 8-row group
    const int brow = ((wg / nig) << 3) + (wg & 7);
    const int bcol = (wg % nig) >> 3;
    const int row0 = brow * 128, col0 = bcol * 128;

    const int wm = (wave >> 1) * 64, wn = (wave & 1) * 64;
    const int srow = lane >> 2;
    const int scol = (lane & 3) * 8;

    f32x4 acc[4][4];
    for (int i = 0; i < 4; ++i)
        for (int j = 0; j < 4; ++j)
            for (int r = 0; r < 4; ++r) acc[i][j][r] = 0.f;

    auto stage = [&](int k0, int bufi) {
        for (int c = 0; c < 2; ++c) {
            const int chunk = wave * 2 + c;
            const int r = chunk * 16 + srow;
            async_cp16(A  + (size_t)(row0 + r) * lda + k0 + scol, &As[bufi][chunk * 512]);
            async_cp16(Bt + (size_t)(col0 + r) * ldb + k0 + scol, &Bs[bufi][chunk * 512]);
        }
    };

    const int nk = K / 32;
    stage(0, 0);
    for (int ki = 0; ki < nk; ++ki) {
        __syncthreads();                    // drains stage ki; frees buf (ki+1)&1
        if (ki + 1 < nk) stage((ki + 1) * 32, (ki + 1) & 1);
        const int bi = ki & 1;
        short8 af[4], bfr[4];
        for (int t = 0; t < 4; ++t) {
            af[t]  = *(const short8*)&As[bi][(wm + t * 16 + l16) * 32 + quad * 8];
            bfr[t] = *(const short8*)&Bs[bi][(wn + t * 16 + l16) * 32 + quad * 8];
        }
        for (int i = 0; i < 4; ++i)
            for (int j = 0; j < 4; ++j)
                acc[i][j] = __builtin_amdgcn_mfma_f32_16x16x32_bf16(
                    af[i], bfr[j], acc[i][j], 0, 0, 0);
    }

    const int rbase = row0 + wm + quad * 4;
    const int cbase = col0 + wn + l16;
    if (OUT_F32) {
        float* C = (float*)Cout;
        for (int i = 0; i < 4; ++i)
            for (int j = 0; j < 4; ++j)
                for (int r = 0; r < 4; ++r)
                    C[(size_t)(rbase + i * 16 + r) * ldc + cbase + j * 16] = acc[i][j][r];
    } else if (KVMODE && col0 < 2048) {
        // K-half: RoPE fused on f32 acc (partner value from lane^1)
        bf16* C = (bf16*)Cout;
        for (int i = 0; i < 4; ++i)
            for (int r = 0; r < 4; ++r) {
                const int s = (rbase + i * 16 + r) & (SS - 1);
                const float* fro = freqs + (size_t)s * 64;
                for (int j = 0; j < 4; ++j) {
                    const int d = wn + j * 16 + l16;     // col&127 (no wrap)
                    const float f = fro[d >> 1];
                    const float cs = __cosf(f), sn = __sinf(f);
                    const float v  = acc[i][j][r];
                    const float vp = __shfl_xor(v, 1);
                    const float o  = (l16 & 1) ? (vp * sn + v * cs)
                                               : (v * cs - vp * sn);
                    C[(size_t)(rbase + i * 16 + r) * ldc + cbase + j * 16] =
                        __float2bfloat16(o);
                }
            }
    } else if (KVMODE) {
        // V-half: direct V^T store to VTg[bh][d][s], granule-swizzled (g^(d&7))
        const int h = (col0 - 2048) >> 7;    // block-uniform
        const int b = row0 >> 11;            // block-uniform
        bf16* Vt = VTg + (size_t)(b * NH + h) * HDD * SS;
        for (int i = 0; i < 4; ++i) {
            const int s4 = (rbase + i * 16) & (SS - 1);   // multiple of 4
            const int g  = (s4 >> 3) & 7;
            const int sb = (s4 & ~63) | (s4 & 7);
            for (int j = 0; j < 4; ++j) {
                const int d = wn + j * 16 + l16;
                ushort4 pv;
                pv.x = bf_bits(__float2bfloat16(acc[i][j][0]));
                pv.y = bf_bits(__float2bfloat16(acc[i][j][1]));
                pv.z = bf_bits(__float2bfloat16(acc[i][j][2]));
                pv.w = bf_bits(__float2bfloat16(acc[i][j][3]));
                *(ushort4*)(Vt + (size_t)d * SS + sb + ((g ^ (d & 7)) << 3)) = pv;
            }
        }
    } else {
        bf16* C = (bf16*)Cout;
        for (int i = 0; i < 4; ++i)
            for (int j = 0; j < 4; ++j)
                for (int r = 0; r < 4; ++r)
                    C[(size_t)(rbase + i * 16 + r) * ldc + cbase + j * 16] =
                        __float2bfloat16(acc[i][j][r]);
    }
}

// ------------- causal flash attention v2b (proven 74.4 us): 4 waves, 32x32 MFMA,
// swapped QK^T, in-register softmax. Cross-half exchanges via __shfl_xor;
// P->bf16 via scalar casts. Lane owns one q-row (col l32 of S^T). LDS 66 KB.
// K now lives in a dense [tok][2048] buffer (krs=2048).
__global__ __launch_bounds__(256, 2) void flash_attn(
    const bf16* __restrict__ QC, const bf16* __restrict__ KV,
    const bf16* __restrict__ VTg, const float* __restrict__ freqs,
    bf16* __restrict__ O) {
    const int j = blockIdx.x;
    const int bh = (j >> 3) & 31, q3 = j & 7;
    const int qt = (j & 256) ? q3 : 15 - q3;
    const int h = bh & (NH - 1), b = bh >> 4;
    const int q0 = qt * 128;
    const int tid = threadIdx.x, lane = tid & 63, wave = tid >> 6;
    const int l32 = lane & 31, hi = lane >> 5;

    __shared__ __align__(16) char smem[66048];
    bf16*  KsB  = (bf16*)smem;              // [2][64*128]
    bf16*  VtB  = (bf16*)(smem + 32768);    // [2][128*64]
    float* RedS = (float*)(smem + 65536);   // [4][32]

    const bf16* Kb  = KV  + (size_t)b * SS * 2048 + h * HDD;
    const bf16* VTb = VTg + (size_t)bh * HDD * SS;
    const int krs = 2048;

    // ---- Q B-frags (col=q=l32, k-elems d=dk*16+hi*8+e), RoPE+scale fused ----
    const float QS = 0.08838834764831845f * 1.4426950408889634f;  // 1/sqrt(HD)*log2e
    const int qrow = q0 + wave * 32 + l32;
    short8 qf[8];
    {
        const bf16* qp = QC + (size_t)(b * SS + qrow) * QRS + h * HDD;
#pragma unroll
        for (int dk = 0; dk < 8; ++dk) {
            short8 v = *(const short8*)(qp + dk * 16 + hi * 8);
            const float4 f = *(const float4*)&freqs[(size_t)qrow * 64 + dk * 8 + hi * 4];
            const float fr[4] = {f.x, f.y, f.z, f.w};
            const bf16* ve = (const bf16*)&v;
            bf16* oe = (bf16*)&qf[dk];
#pragma unroll
            for (int i2 = 0; i2 < 4; ++i2) {
                const float cs = __cosf(fr[i2]), sn = __sinf(fr[i2]);
                const float t0 = __bfloat162float(ve[2 * i2]);
                const float t1 = __bfloat162float(ve[2 * i2 + 1]);
                oe[2 * i2]     = __float2bfloat16((t0 * cs - t1 * sn) * QS);
                oe[2 * i2 + 1] = __float2bfloat16((t0 * sn + t1 * cs) * QS);
            }
        }
    }

    // ---- staging: K with inverse-swizzled source (linear LDS dest),
    //      V straight copy of pre-swizzled VTg rows ----
    auto stage = [&](int kt, int bufi) {
        const int k0 = kt * 64;
#pragma unroll
        for (int ii = 0; ii < 4; ++ii) {
            const int i = wave * 4 + ii;
            const int krow = 4 * i + (lane >> 4);
            const int csrc = (lane & 15) ^ (krow & 7);
            async_cp16(Kb + (size_t)(k0 + krow) * krs + csrc * 8,
                       KsB + bufi * 8192 + i * 512);
            const int d = 8 * i + (lane >> 3);
            async_cp16(VTb + (size_t)d * SS + k0 + (lane & 7) * 8,
                       VtB + bufi * 8192 + i * 512);
        }
    };

    f32x16 accO[4];
#pragma unroll
    for (int d = 0; d < 4; ++d)
#pragma unroll
        for (int r = 0; r < 16; ++r) accO[d][r] = 0.f;
    float m_r = -1e30f, l_r = 0.f;

    const int ktMax = 2 * qt + 1;
    const int qwb = q0 + wave * 32;      // wave's first q row

    stage(0, 0);
    for (int kt = 0; kt <= ktMax; ++kt) {
        const int k0 = kt * 64;
        __syncthreads();                    // drains stage kt; frees buf (kt+1)&1
        if (kt < ktMax) stage(kt + 1, (kt + 1) & 1);
        const int bi = kt & 1;

        if (k0 > qwb + 31) continue;        // tile entirely above diagonal (wave-uniform)

        // ---- S^T = K Q^T : lane holds 32 kv-scores for q-row l32 ----
        f32x16 st[2];
#pragma unroll
        for (int t = 0; t < 2; ++t)
#pragma unroll
            for (int r = 0; r < 16; ++r) st[t][r] = 0.f;
        __builtin_amdgcn_s_setprio(1);
#pragma unroll
        for (int dk = 0; dk < 8; ++dk)
#pragma unroll
            for (int t = 0; t < 2; ++t) {
                const int rd = t * 32 + l32;
                short8 kf = *(const short8*)
                    &KsB[bi * 8192 + rd * 128 + ((((dk << 1) | hi) ^ (rd & 7)) << 3)];
                st[t] = __builtin_amdgcn_mfma_f32_32x32x16_bf16(
                    kf, qf[dk], st[t], 0, 0, 0);
            }
        __builtin_amdgcn_s_setprio(0);

        float p[32];
#pragma unroll
        for (int t = 0; t < 2; ++t)
#pragma unroll
            for (int r = 0; r < 16; ++r) p[t * 16 + r] = st[t][r];

        // ---- causal mask (boundary tiles only; wave-uniform branch) ----
        if (k0 + 63 > qwb) {
#pragma unroll
            for (int t = 0; t < 2; ++t)
#pragma unroll
                for (int r = 0; r < 16; ++r) {
                    const int kv = k0 + t * 32 + (r & 3) + 8 * (r >> 2) + 4 * hi;
                    if (kv > qrow) p[t * 16 + r] = -1e30f;
                }
        }

        // ---- row max: lane-local tree + cross-half shfl ----
        float mt[16];
#pragma unroll
        for (int n = 0; n < 16; ++n) mt[n] = fmaxf(p[n], p[n + 16]);
#pragma unroll
        for (int n = 0; n < 8; ++n) mt[n] = fmaxf(mt[n], mt[n + 8]);
#pragma unroll
        for (int n = 0; n < 4; ++n) mt[n] = fmaxf(mt[n], mt[n + 4]);
        float mx = fmaxf(fmaxf(mt[0], mt[1]), fmaxf(mt[2], mt[3]));
        const float rmax = fmaxf(mx, __shfl_xor(mx, 32));

        // ---- defer-max (T13): rescale only when max grows > 2^8 ----
        const bool grow = rmax > m_r + 8.f;
        if (__any(grow)) {
            const float mnew = fmaxf(m_r, rmax);
            const float alpha = EXP2F(m_r - mnew);
            m_r = mnew;
            l_r *= alpha;
            RedS[wave * 32 + l32] = alpha;      // both halves write identical value
            __builtin_amdgcn_s_waitcnt(0xc07f); // lgkmcnt(0): own-wave writes visible
#pragma unroll
            for (int r = 0; r < 16; ++r) {
                const float av = RedS[wave * 32 + ((r & 3) + 8 * (r >> 2) + 4 * hi)];
#pragma unroll
                for (int d = 0; d < 4; ++d) accO[d][r] *= av;
            }
        }

        // ---- P = exp2(S - m); row sum (tree + cross-half shfl) ----
#pragma unroll
        for (int r = 0; r < 32; ++r) p[r] = EXP2F(p[r] - m_r);
        float sa[16];
#pragma unroll
        for (int n = 0; n < 16; ++n) sa[n] = p[n] + p[n + 16];
#pragma unroll
        for (int n = 0; n < 8; ++n) sa[n] += sa[n + 8];
#pragma unroll
        for (int n = 0; n < 4; ++n) sa[n] += sa[n + 4];
        float ps = (sa[0] + sa[1]) + (sa[2] + sa[3]);
        l_r += ps + __shfl_xor(ps, 32);

        // ---- P -> packed bf16 pairs (scalar casts; compiler emits cvt_pk) ----
        unsigned int pk[16];
#pragma unroll
        for (int n = 0; n < 16; ++n) {
            const unsigned int lo = bf_bits(__float2bfloat16(p[2 * n]));
            const unsigned int hl = bf_bits(__float2bfloat16(p[2 * n + 1]));
            pk[n] = lo | (hl << 16);
        }

        // ---- O += P V  (A-frags assembled via cross-half shfl) ----
#pragma unroll
        for (int m = 0; m < 4; ++m) {
            const int A0 = 4 * m;
            const unsigned int op0 = __shfl_xor(pk[A0 + 0], 32);
            const unsigned int op1 = __shfl_xor(pk[A0 + 1], 32);
            const unsigned int op2 = __shfl_xor(pk[A0 + 2], 32);
            const unsigned int op3 = __shfl_xor(pk[A0 + 3], 32);
            union { unsigned int w[4]; short8 s; } fr;
            fr.w[0] = hi ? op2 : pk[A0 + 0];
            fr.w[1] = hi ? op3 : pk[A0 + 1];
            fr.w[2] = hi ? pk[A0 + 2] : op0;
            fr.w[3] = hi ? pk[A0 + 3] : op1;
            __builtin_amdgcn_s_setprio(1);
#pragma unroll
            for (int db = 0; db < 4; ++db) {
                const int d = db * 32 + l32;
                short8 vf = *(const short8*)
                    &VtB[bi * 8192 + d * 64 + ((((m << 1) | hi) ^ (d & 7)) << 3)];
                accO[db] = __builtin_amdgcn_mfma_f32_32x32x16_bf16(
                    fr.s, vf, accO[db], 0, 0, 0);
            }
            __builtin_amdgcn_s_setprio(0);
        }
    }

    // ---- epilogue: 1/l per q-row, LDS bounce, coalesced bf16 stores ----
    const float invl = 1.f / l_r;
    RedS[wave * 32 + l32] = invl;
    __builtin_amdgcn_s_waitcnt(0xc07f);     // lgkmcnt(0): own-wave writes visible
    bf16* Ob = O + (size_t)b * SS * DD + h * HDD;
#pragma unroll
    for (int r = 0; r < 16; ++r) {
        const int row = (r & 3) + 8 * (r >> 2) + 4 * hi;
        const float iv = RedS[wave * 32 + row];
        const size_t ro = (size_t)(q0 + wave * 32 + row) * DD;
#pragma unroll
        for (int db = 0; db < 4; ++db)
            Ob[ro + db * 32 + l32] = __float2bfloat16(accO[db][r] * iv);
    }
}

extern "C" void kernel_launch(void* const* d_in, const int* in_sizes, int n_in,
                              void* d_out, int out_size, void* d_ws, size_t ws_size,
                              hipStream_t stream) {
    (void)in_sizes; (void)n_in; (void)out_size; (void)ws_size;
    const float* x     = (const float*)d_in[0];
    const float* freqs = (const float*)d_in[1];
    // d_in[2] = mask: exactly causal 0/-1e9 -> applied analytically in flash_attn
    const float* Wq    = (const float*)d_in[3];
    const float* Wdown = (const float*)d_in[4];
    const float* Wkup  = (const float*)d_in[5];
    const float* Wvup  = (const float*)d_in[6];
    const float* Wo    = (const float*)d_in[7];
    float* out = (float*)d_out;

    char* ws = (char*)d_ws;
    size_t off = 0;
    auto take = [&](size_t bytes) -> void* {
        void* p = ws + off;
        off += (bytes + 255) & ~(size_t)255;
        return p;
    };
    bf16* xb    = (bf16*)take((size_t)MR * DD * 2);         // 16.8 MB (later: attn)
    bf16* WqdT  = (bf16*)take((size_t)QRS * DD * 2);        // 10.5 MB
    bf16* WkvT  = (bf16*)take((size_t)2 * DD * LATD * 2);   //  4.2 MB
    bf16* WoT   = (bf16*)take((size_t)DD * DD * 2);         //  8.4 MB (own buffer)
    bf16* QC    = (bf16*)take((size_t)MR * QRS * 2);        // 21.0 MB [Q 2048 | ckv 512]
    bf16* KVb   = (bf16*)take((size_t)MR * DD * 2);         // 16.8 MB K only [tok][2048]
    bf16* VTg   = (bf16*)take((size_t)BB * NH * HDD * SS * 2); // 16.8 MB (~94.5 MB total)
    bf16* attn  = xb;      // xb dead after QC gemm

    // cast x + all 5 weight transposes in one launch
    prep<<<19456, 256, 0, stream>>>(x, xb, Wq, Wdown, Wkup, Wvup, Wo,
                                    WqdT, WkvT, WoT);

    // [Q | c_kv] = x [Wq | Wdown]   (M=4096, N=2560, K=2048) -> 640 blocks
    gemm_bt<false, false><<<(QRS / 128) * (MR / 128), 256, 0, stream>>>(
        xb, WqdT, QC, MR, QRS, DD, DD, DD, QRS, nullptr, nullptr);
    // [K | V] = c_kv [Wkup | Wvup]  (M=4096, N=4096, K=512) -> 1024 blocks
    // K-half: RoPE fused, written to KVb[tok][2048]; V-half: direct V^T to VTg.
    gemm_bt<false, true><<<(2 * DD / 128) * (MR / 128), 256, 0, stream>>>(
        QC + DD, WkvT, KVb, MR, 2 * DD, LATD, QRS, LATD, DD, freqs, VTg);

    flash_attn<<<512, 256, 0, stream>>>(QC, KVb, VTg, freqs, attn);

    // out = attn Wo (fp32 epilogue straight to d_out)  -> 512 blocks
    gemm_bt<true, false><<<(DD / 128) * (MR / 128), 256, 0, stream>>>(
        attn, WoT, out, MR, DD, DD, DD, DD, DD, nullptr, nullptr);
}